// Round 7
// baseline (12637.694 us; speedup 1.0000x reference)
//
#include <hip/hip_runtime.h>
#include <cmath>

#define NBAT 32
#define PADH 36   // h_lds row pad (floats)
#define NWG  64   // lstm workgroups (8 j each)

__device__ __forceinline__ float sigf(float x) { return 1.f / (1.f + __expf(-x)); }

// XOR swizzle on 16B chunks: bijective within 32-chunk row, spreads stride-8
// float reads 2-per-bank-quad (free) instead of 4-way conflicts.
__device__ __forceinline__ int gswz(int c) { return c ^ (c >> 3); }

// ---------------------------------------------------------------------------
// GEMM: C[M,N] = A[M,K] @ B[N,K]^T + bias1 (+ bias2), 128x128 tile, 8x8/thread
// gmode=1: scatter-store into G layout [t][g][b][j] (row m = b*512+t, col n = g*512+j)
// ---------------------------------------------------------------------------
__global__ __launch_bounds__(256, 2) void gemm128(
    const float* __restrict__ A, const float* __restrict__ B,
    const float* __restrict__ bias1, const float* __restrict__ bias2,
    float* __restrict__ C, int M, int N, int K, int gmode) {
  __shared__ __align__(16) float As[8][132];
  __shared__ __align__(16) float Bs[8][132];
  const int tid = threadIdx.x;
  const int n0 = blockIdx.x * 128, m0 = blockIdx.y * 128;
  const int lm = tid & 127, kh = tid >> 7;   // staging: row, k-half
  const int tx = tid & 15, ty = tid >> 4;    // compute: col group, row group
  // swizzled scalar-store column for staging
  const int colp = (gswz(lm >> 2) << 2) | (lm & 3);
  // swizzled float4 read columns
  const int ca0 = gswz(2 * ty) * 4, ca1 = gswz(2 * ty + 1) * 4;
  const int cb0 = gswz(2 * tx) * 4, cb1 = gswz(2 * tx + 1) * 4;
  const float* Ap = A + (size_t)(m0 + lm) * K + kh * 4;
  const float* Bp = B + (size_t)(n0 + lm) * K + kh * 4;
  float acc[8][8] = {};
  float4 av = *(const float4*)Ap;
  float4 bv = *(const float4*)Bp;
  const int nk = K / 8;
  for (int kt = 0; kt < nk; ++kt) {
    __syncthreads();
    As[kh*4+0][colp] = av.x; As[kh*4+1][colp] = av.y;
    As[kh*4+2][colp] = av.z; As[kh*4+3][colp] = av.w;
    Bs[kh*4+0][colp] = bv.x; Bs[kh*4+1][colp] = bv.y;
    Bs[kh*4+2][colp] = bv.z; Bs[kh*4+3][colp] = bv.w;
    __syncthreads();
    if (kt + 1 < nk) {
      av = *(const float4*)(Ap + (kt + 1) * 8);
      bv = *(const float4*)(Bp + (kt + 1) * 8);
    }
#pragma unroll
    for (int kk = 0; kk < 8; ++kk) {
      float4 a0 = *(const float4*)&As[kk][ca0];
      float4 a1 = *(const float4*)&As[kk][ca1];
      float4 b0 = *(const float4*)&Bs[kk][cb0];
      float4 b1 = *(const float4*)&Bs[kk][cb1];
      float ar[8] = {a0.x,a0.y,a0.z,a0.w,a1.x,a1.y,a1.z,a1.w};
      float br[8] = {b0.x,b0.y,b0.z,b0.w,b1.x,b1.y,b1.z,b1.w};
#pragma unroll
      for (int i = 0; i < 8; ++i)
#pragma unroll
        for (int j = 0; j < 8; ++j)
          acc[i][j] += ar[i] * br[j];
    }
  }
  const int nc = n0 + tx * 8;
  float bb[8];
  { float4 c0 = *(const float4*)&bias1[nc], c1 = *(const float4*)&bias1[nc+4];
    bb[0]=c0.x; bb[1]=c0.y; bb[2]=c0.z; bb[3]=c0.w;
    bb[4]=c1.x; bb[5]=c1.y; bb[6]=c1.z; bb[7]=c1.w; }
  if (bias2) {
    float4 c0 = *(const float4*)&bias2[nc], c1 = *(const float4*)&bias2[nc+4];
    bb[0]+=c0.x; bb[1]+=c0.y; bb[2]+=c0.z; bb[3]+=c0.w;
    bb[4]+=c1.x; bb[5]+=c1.y; bb[6]+=c1.z; bb[7]+=c1.w;
  }
#pragma unroll
  for (int i = 0; i < 8; ++i) {
    const int m = m0 + ty * 8 + i;
    float4 o0 = make_float4(acc[i][0]+bb[0], acc[i][1]+bb[1], acc[i][2]+bb[2], acc[i][3]+bb[3]);
    float4 o1 = make_float4(acc[i][4]+bb[4], acc[i][5]+bb[5], acc[i][6]+bb[6], acc[i][7]+bb[7]);
    if (gmode) {
      const int b = m >> 9, tt = m & 511, g = nc >> 9, j = nc & 511;
      const size_t base = ((size_t)(tt * 4 + g) * 32 + b) * 512 + j;
      *(float4*)&C[base] = o0; *(float4*)&C[base + 4] = o1;
    } else {
      *(float4*)&C[(size_t)m * N + nc] = o0;
      *(float4*)&C[(size_t)m * N + nc + 4] = o1;
    }
  }
}

// ---------------------------------------------------------------------------
// Persistent LSTM recurrence v2: 64 WGs x 512 threads, 8 j/WG.
// Cross-WG traffic (hT, flags) via sc0 sc1 only (LLC = coherence point).
// Single flag per WG: owners store h (sc0 sc1) -> vmcnt(0) -> __syncthreads
// (all threads' stores LLC-acked before anyone passes) -> tid0 flag store.
// Consumer: 64 lanes poll 64 flags (1 load/lane) -> barrier -> split-half
// staging (8 dwordx4/thread, vmcnt(4) -> FMA rows 0..255 overlaps 2nd half).
// ---------------------------------------------------------------------------
__global__ __launch_bounds__(512, 1) void lstm_rec(
    const float* __restrict__ G,     // [512 t][4 g][32 b][512 j]
    const float* __restrict__ Whh,   // [2048][512]
    float* __restrict__ Hout,        // [(b*512+t)*512 + j]
    float* __restrict__ hT,          // [2][512 j][32 b]
    int* __restrict__ flags,         // [64] (1 per WG)
    int gen_base) {
  __shared__ __align__(16) float h_lds[512 * PADH];
  __shared__ __align__(16) float red2[8][16][36];
  __shared__ __align__(16) float pre_s[2][4][32][8];

  const int tid = threadIdx.x;
  const int wg  = blockIdx.x;
  const int j0  = wg * 8;
  const int lane = tid & 63;
  const int wv   = tid >> 6;        // 0..7

  // FMA decode: half = j-half (jj 0-3 / 4-7)
  const int half = tid >> 8;
  const int sub  = tid & 255;
  const int kq   = sub >> 4;        // 0..15
  const int jj   = half * 4 + (sub & 3);
  const int b0   = ((sub >> 2) & 3) * 8;

  // Whh slice into registers: w_reg[i][g] = Whh[g*512 + j0 + jj][kq + 16*i]
  float w_reg[32][4];
#pragma unroll
  for (int g = 0; g < 4; ++g) {
    const float* wrow = Whh + (size_t)(g * 512 + j0 + jj) * 512 + kq;
#pragma unroll
    for (int i = 0; i < 32; ++i) w_reg[i][g] = wrow[16 * i];
  }

  // owner decode (tid < 256): one (batch, j) output per thread
  const int ob  = tid >> 3;             // 0..31
  const int ojj = tid & 7;              // 0..7
  const int rl  = (ob >> 3) * 4 + (ojj & 3);
  const int rbl = ob & 7;
  const int rwb = (ojj >> 2) * 4;       // wave base for combine
  float c_reg = 0.f;

  // G prefetch decode (tid >= 256): 256 threads cover 4g x 32b x 2 float4
  const int pid = tid - 256;
  const int pg = pid >> 6, pb = (pid >> 1) & 31, pjw = pid & 1;
  float4 gpre;
  if (tid >= 256)
    gpre = *(const float4*)&G[(((size_t)0 * 4 + pg) * 32 + pb) * 512 + j0 + pjw * 4];

  for (int t = 0; t < 512; ++t) {
    const int buf = t & 1;

    // commit prefetched G(t) to LDS (compiler waits gpre; issued last step)
    if (tid >= 256)
      *(float4*)&pre_s[buf][pg][pb][pjw * 4] = gpre;

    // 64 lanes poll 64 per-WG flags (sc0 sc1, 1 load/lane)
    if (tid < 64) {
      const int target = gen_base + t;
      const int* fp = flags + tid;
      for (;;) {
        int f0;
        asm volatile("global_load_dword %0, %1, off sc0 sc1\n\ts_waitcnt vmcnt(0)"
                     : "=&v"(f0) : "v"(fp) : "memory");
        if (__all(f0 >= target)) break;
        __builtin_amdgcn_s_sleep(1);
      }
    }
    __syncthreads();

    // stage h^t: 512 thr x 8 dwordx4 = 4096 float4 = 16384 floats (FULL).
    const float* hcur = hT + (size_t)buf * (512 * NBAT);
    float4 hv[8];
#pragma unroll
    for (int it = 0; it < 8; ++it)
      asm volatile("global_load_dwordx4 %0, %1, off sc0 sc1"
                   : "=&v"(hv[it]) : "v"(hcur + (size_t)(tid + it * 512) * 4));
    asm volatile("s_waitcnt vmcnt(4)" ::: "memory");   // first 4 (rows 0..255)
    __builtin_amdgcn_sched_barrier(0);
#pragma unroll
    for (int it = 0; it < 4; ++it) {
      const int idx4 = tid + it * 512;
      *(float4*)&h_lds[(idx4 >> 3) * PADH + (idx4 & 7) * 4] = hv[it];
    }
    __syncthreads();

    // FMA first half (k rows 0..255) while second half in flight
    float acc[8][4] = {};
#pragma unroll
    for (int i = 0; i < 16; ++i) {
      const int k = kq + 16 * i;
      const float* hp = &h_lds[k * PADH + b0];
      float4 h0 = *(const float4*)hp;
      float4 h1 = *(const float4*)(hp + 4);
      float hv8[8] = {h0.x, h0.y, h0.z, h0.w, h1.x, h1.y, h1.z, h1.w};
#pragma unroll
      for (int bi = 0; bi < 8; ++bi)
#pragma unroll
        for (int g = 0; g < 4; ++g)
          acc[bi][g] += hv8[bi] * w_reg[i][g];
    }
    asm volatile("s_waitcnt vmcnt(0)" ::: "memory");
    __builtin_amdgcn_sched_barrier(0);
#pragma unroll
    for (int it = 4; it < 8; ++it) {   // rows 256..511, disjoint from FMA-A reads
      const int idx4 = tid + it * 512;
      *(float4*)&h_lds[(idx4 >> 3) * PADH + (idx4 & 7) * 4] = hv[it];
    }
    __syncthreads();

    // issue G prefetch for t+1 (latency hides across rest of step + next poll)
    if (tid >= 256 && t + 1 < 512)
      gpre = *(const float4*)&G[(((size_t)(t + 1) * 4 + pg) * 32 + pb) * 512 + j0 + pjw * 4];

    // FMA second half (k rows 256..511)
#pragma unroll
    for (int i = 16; i < 32; ++i) {
      const int k = kq + 16 * i;
      const float* hp = &h_lds[k * PADH + b0];
      float4 h0 = *(const float4*)hp;
      float4 h1 = *(const float4*)(hp + 4);
      float hv8[8] = {h0.x, h0.y, h0.z, h0.w, h1.x, h1.y, h1.z, h1.w};
#pragma unroll
      for (int bi = 0; bi < 8; ++bi)
#pragma unroll
        for (int g = 0; g < 4; ++g)
          acc[bi][g] += hv8[bi] * w_reg[i][g];
    }

    // wave-local reduce over 4 kq slices (lane bits 4,5)
#pragma unroll
    for (int bi = 0; bi < 8; ++bi)
#pragma unroll
      for (int g = 0; g < 4; ++g) {
        float v = acc[bi][g];
        v += __shfl_down(v, 32, 64);
        v += __shfl_down(v, 16, 64);
        acc[bi][g] = v;
      }
    if (lane < 16) {
#pragma unroll
      for (int e = 0; e < 32; ++e) red2[wv][lane][e] = acc[e >> 2][e & 3];
    }
    __syncthreads();

    // owners (tid<256): cross-wave combine + LSTM cell + LLC publish
    if (tid < 256) {
      float4 s0 = *(const float4*)&red2[rwb + 0][rl][rbl * 4];
      float4 s1 = *(const float4*)&red2[rwb + 1][rl][rbl * 4];
      float4 s2 = *(const float4*)&red2[rwb + 2][rl][rbl * 4];
      float4 s3 = *(const float4*)&red2[rwb + 3][rl][rbl * 4];
      const float gi = (s0.x + s1.x) + (s2.x + s3.x) + pre_s[buf][0][ob][ojj];
      const float gf = (s0.y + s1.y) + (s2.y + s3.y) + pre_s[buf][1][ob][ojj];
      const float gg = (s0.z + s1.z) + (s2.z + s3.z) + pre_s[buf][2][ob][ojj];
      const float go = (s0.w + s1.w) + (s2.w + s3.w) + pre_s[buf][3][ob][ojj];
      const float iv = sigf(gi);
      const float fv = sigf(gf);
      const float gv = tanhf(gg);
      const float ov = sigf(go);
      const float c = fv * c_reg + iv * gv;
      c_reg = c;
      const float h = ov * tanhf(c);
      float* hnxt = hT + (size_t)((t + 1) & 1) * (512 * NBAT);
      asm volatile("global_store_dword %0, %1, off sc0 sc1"
                   :: "v"(&hnxt[(j0 + ojj) * 32 + ob]), "v"(h) : "memory");
      Hout[((size_t)ob * 512 + t) * 512 + j0 + ojj] = h;
      asm volatile("s_waitcnt vmcnt(0)" ::: "memory");  // h LLC-acked
    }
    __syncthreads();   // all owners acked before flag
    if (tid == 0) {
      const int val = gen_base + t + 1;
      asm volatile("global_store_dword %0, %1, off sc0 sc1"
                   :: "v"(&flags[wg]), "v"(val) : "memory");
    }
  }
}

// ---------------------------------------------------------------------------
// Fused attention: out[b,q] = (1/8)*sum_h softmax_{d<=q}(QK^T/8)[d]*H2[b,q,d]*Wo[d] + bo
// ---------------------------------------------------------------------------
__device__ __forceinline__ int kswz(int row, int col) {
  return row * 64 + (col ^ (((row >> 2) & 7) << 2));
}

__global__ __launch_bounds__(256) void attn_kernel(
    const float* __restrict__ Qg, const float* __restrict__ Kg,
    const float* __restrict__ H2, const float* __restrict__ Wo,
    const float* __restrict__ bo, float* __restrict__ out) {
  __shared__ float Ks[64 * 64];
  __shared__ float part[4][16][68];
  __shared__ float s[16][512];
  __shared__ float Wo_s[512];

  const int tid = threadIdx.x;
  const int qt = blockIdx.x, b = blockIdx.y;
  const int q0 = qt * 16;
  const int dd = tid >> 6, qq = (tid >> 4) & 3, kq = tid & 15;
  const int srow = tid >> 4, slane = tid & 15;

  Wo_s[tid] = Wo[tid];
  Wo_s[256 + tid] = Wo[256 + tid];

  float out_reg = 0.f;
  const int kcmax = (q0 + 15) >> 6;

  for (int h = 0; h < 8; ++h) {
    float qreg[4][16];
#pragma unroll
    for (int r = 0; r < 4; ++r) {
      const float* qrow = Qg + ((size_t)(b * 512) + q0 + qq * 4 + r) * 512 + h * 64 + dd * 16;
#pragma unroll
      for (int i = 0; i < 16; i += 4) {
        float4 v = *(const float4*)(qrow + i);
        qreg[r][i] = v.x; qreg[r][i+1] = v.y; qreg[r][i+2] = v.z; qreg[r][i+3] = v.w;
      }
    }

    for (int kc = 0; kc <= kcmax; ++kc) {
      __syncthreads();
#pragma unroll
      for (int it = 0; it < 4; ++it) {
        const int f = tid * 4 + it * 1024;
        const int kk = f >> 6, d = f & 63;
        float4 v = *(const float4*)(Kg + ((size_t)(b * 512) + kc * 64 + kk) * 512 + h * 64 + d);
        Ks[kswz(d + 0, kk)] = v.x;
        Ks[kswz(d + 1, kk)] = v.y;
        Ks[kswz(d + 2, kk)] = v.z;
        Ks[kswz(d + 3, kk)] = v.w;
      }
      __syncthreads();

      float acc[4][4] = {};
#pragma unroll
      for (int i = 0; i < 16; ++i) {
        const int row = dd * 16 + i;
        float4 k4 = *(const float4*)&Ks[kswz(row, kq * 4)];
#pragma unroll
        for (int r = 0; r < 4; ++r) {
          acc[r][0] += qreg[r][i] * k4.x;
          acc[r][1] += qreg[r][i] * k4.y;
          acc[r][2] += qreg[r][i] * k4.z;
          acc[r][3] += qreg[r][i] * k4.w;
        }
      }
#pragma unroll
      for (int r = 0; r < 4; ++r)
        *(float4*)&part[dd][qq * 4 + r][kq * 4] =
            make_float4(acc[r][0], acc[r][1], acc[r][2], acc[r][3]);
      __syncthreads();
      {
        const int qi = tid >> 4, c = tid & 15;
        float4 p0 = *(const float4*)&part[0][qi][c * 4];
        float4 p1 = *(const float4*)&part[1][qi][c * 4];
        float4 p2 = *(const float4*)&part[2][qi][c * 4];
        float4 p3 = *(const float4*)&part[3][qi][c * 4];
        float4 r;
        r.x = ((p0.x + p1.x) + (p2.x + p3.x)) * 0.125f;
        r.y = ((p0.y + p1.y) + (p2.y + p3.y)) * 0.125f;
        r.z = ((p0.z + p1.z) + (p2.z + p3.z)) * 0.125f;
        r.w = ((p0.w + p1.w) + (p2.w + p3.w)) * 0.125f;
        *(float4*)&s[qi][kc * 64 + c * 4] = r;
      }
    }
    __syncthreads();

    const int q = q0 + srow;
    const int count = q + 1;
    const float* sp = &s[srow][0];
    float m = -1e30f;
    for (int d = slane; d < count; d += 16) m = fmaxf(m, sp[d]);
    m = fmaxf(m, __shfl_xor(m, 1, 64));
    m = fmaxf(m, __shfl_xor(m, 2, 64));
    m = fmaxf(m, __shfl_xor(m, 4, 64));
    m = fmaxf(m, __shfl_xor(m, 8, 64));
    float z = 0.f, zw = 0.f;
    const float* h2row = H2 + ((size_t)(b * 512) + q) * 512;
    for (int d = slane; d < count; d += 16) {
      const float e = __expf(sp[d] - m);
      z += e;
      zw += e * h2row[d] * Wo_s[d];
    }
    z += __shfl_xor(z, 1, 64); z += __shfl_xor(z, 2, 64);
    z += __shfl_xor(z, 4, 64); z += __shfl_xor(z, 8, 64);
    zw += __shfl_xor(zw, 1, 64); zw += __shfl_xor(zw, 2, 64);
    zw += __shfl_xor(zw, 4, 64); zw += __shfl_xor(zw, 8, 64);
    out_reg += zw / z;
    __syncthreads();
  }

  if (slane == 0)
    out[b * 512 + q0 + srow] = out_reg * 0.125f + bo[0];
}

// ---------------------------------------------------------------------------
extern "C" void kernel_launch(void* const* d_in, const int* in_sizes, int n_in,
                              void* d_out, int out_size, void* d_ws, size_t ws_size,
                              hipStream_t stream) {
  const float* x    = (const float*)d_in[0];
  const float* Wih0 = (const float*)d_in[1];
  const float* Whh0 = (const float*)d_in[2];
  const float* bih0 = (const float*)d_in[3];
  const float* bhh0 = (const float*)d_in[4];
  const float* Wih1 = (const float*)d_in[5];
  const float* Whh1 = (const float*)d_in[6];
  const float* bih1 = (const float*)d_in[7];
  const float* bhh1 = (const float*)d_in[8];
  const float* Wq   = (const float*)d_in[9];
  const float* bq   = (const float*)d_in[10];
  const float* Wk   = (const float*)d_in[11];
  const float* bk   = (const float*)d_in[12];
  const float* Wo   = (const float*)d_in[13];
  const float* bo   = (const float*)d_in[14];
  float* out = (float*)d_out;

  float* ws = (float*)d_ws;
  const size_t M = 16384;
  float* G  = ws;                                  // 16384*2048 floats
  float* H1 = G  + (size_t)16384 * 2048;           // 16384*512
  float* H2 = H1 + (size_t)16384 * 512;            // 16384*512
  float* hT = H2 + (size_t)16384 * 512;            // 2*16384 floats
  int* flags = (int*)(hT + 2 * 16384);             // 64 ints
  float* Qb = H1;   // reuse (H1 dead after layer-1 G gemm)
  float* Kb = G;    // reuse (G dead after layer-1 recurrence)

  // zero h state + flags every call (graph replay safe)
  hipMemsetAsync(hT, 0, (2 * 16384) * sizeof(float) + 64 * sizeof(int), stream);

  // layer 0
  gemm128<<<dim3(2048 / 128, M / 128), 256, 0, stream>>>(x, Wih0, bih0, bhh0, G,
                                                         (int)M, 2048, 256, 1);
  lstm_rec<<<NWG, 512, 0, stream>>>(G, Whh0, H1, hT, flags, 0);

  // layer 1 (re-zero hT only; flags continue monotonically via gen_base)
  hipMemsetAsync(hT, 0, (2 * 16384) * sizeof(float), stream);
  gemm128<<<dim3(2048 / 128, M / 128), 256, 0, stream>>>(H1, Wih1, bih1, bhh1, G,
                                                         (int)M, 2048, 512, 1);
  lstm_rec<<<NWG, 512, 0, stream>>>(G, Whh1, H2, hT, flags, 512);

  // Q/K projections
  gemm128<<<dim3(512 / 128, M / 128), 256, 0, stream>>>(H2, Wq, bq, nullptr, Qb,
                                                        (int)M, 512, 512, 0);
  gemm128<<<dim3(512 / 128, M / 128), 256, 0, stream>>>(H2, Wk, bk, nullptr, Kb,
                                                        (int)M, 512, 512, 0);

  // fused causal attention + head-mean + gated output
  attn_kernel<<<dim3(32, 32), 256, 0, stream>>>(Qb, Kb, H2, Wo, bo, out);
}

// Round 8
// 9064.789 us; speedup vs baseline: 1.3942x; 1.3942x over previous
//
#include <hip/hip_runtime.h>
#include <cmath>

#define NBAT 32
#define PADH 36   // h_lds row pad (floats)
#define NWG  128  // lstm workgroups (4 j each)

__device__ __forceinline__ float sigf(float x) { return 1.f / (1.f + __expf(-x)); }

__device__ __forceinline__ float2 f2fma(float2 a, float s, float2 c) {
  return make_float2(fmaf(a.x, s, c.x), fmaf(a.y, s, c.y));
}

// XOR swizzle on 16B chunks: spreads stride-8 float reads across bank quads.
__device__ __forceinline__ int gswz(int c) { return c ^ (c >> 3); }

// ---------------------------------------------------------------------------
// GEMM: C[M,N] = A[M,K] @ B[N,K]^T + bias1 (+ bias2), 128x128 tile, 8x8/thread
// gmode=1: scatter-store into G layout [t][g][b][j] (row m = b*512+t, col n = g*512+j)
// ---------------------------------------------------------------------------
__global__ __launch_bounds__(256, 2) void gemm128(
    const float* __restrict__ A, const float* __restrict__ B,
    const float* __restrict__ bias1, const float* __restrict__ bias2,
    float* __restrict__ C, int M, int N, int K, int gmode) {
  __shared__ __align__(16) float As[8][132];
  __shared__ __align__(16) float Bs[8][132];
  const int tid = threadIdx.x;
  const int n0 = blockIdx.x * 128, m0 = blockIdx.y * 128;
  const int lm = tid & 127, kh = tid >> 7;   // staging: row, k-half
  const int tx = tid & 15, ty = tid >> 4;    // compute: col group, row group
  const int colp = (gswz(lm >> 2) << 2) | (lm & 3);
  const int ca0 = gswz(2 * ty) * 4, ca1 = gswz(2 * ty + 1) * 4;
  const int cb0 = gswz(2 * tx) * 4, cb1 = gswz(2 * tx + 1) * 4;
  const float* Ap = A + (size_t)(m0 + lm) * K + kh * 4;
  const float* Bp = B + (size_t)(n0 + lm) * K + kh * 4;
  float acc[8][8] = {};
  float4 av = *(const float4*)Ap;
  float4 bv = *(const float4*)Bp;
  const int nk = K / 8;
  for (int kt = 0; kt < nk; ++kt) {
    __syncthreads();
    As[kh*4+0][colp] = av.x; As[kh*4+1][colp] = av.y;
    As[kh*4+2][colp] = av.z; As[kh*4+3][colp] = av.w;
    Bs[kh*4+0][colp] = bv.x; Bs[kh*4+1][colp] = bv.y;
    Bs[kh*4+2][colp] = bv.z; Bs[kh*4+3][colp] = bv.w;
    __syncthreads();
    if (kt + 1 < nk) {
      av = *(const float4*)(Ap + (kt + 1) * 8);
      bv = *(const float4*)(Bp + (kt + 1) * 8);
    }
#pragma unroll
    for (int kk = 0; kk < 8; ++kk) {
      float4 a0 = *(const float4*)&As[kk][ca0];
      float4 a1 = *(const float4*)&As[kk][ca1];
      float4 b0 = *(const float4*)&Bs[kk][cb0];
      float4 b1 = *(const float4*)&Bs[kk][cb1];
      float ar[8] = {a0.x,a0.y,a0.z,a0.w,a1.x,a1.y,a1.z,a1.w};
      float br[8] = {b0.x,b0.y,b0.z,b0.w,b1.x,b1.y,b1.z,b1.w};
#pragma unroll
      for (int i = 0; i < 8; ++i)
#pragma unroll
        for (int j = 0; j < 8; ++j)
          acc[i][j] += ar[i] * br[j];
    }
  }
  const int nc = n0 + tx * 8;
  float bb[8];
  { float4 c0 = *(const float4*)&bias1[nc], c1 = *(const float4*)&bias1[nc+4];
    bb[0]=c0.x; bb[1]=c0.y; bb[2]=c0.z; bb[3]=c0.w;
    bb[4]=c1.x; bb[5]=c1.y; bb[6]=c1.z; bb[7]=c1.w; }
  if (bias2) {
    float4 c0 = *(const float4*)&bias2[nc], c1 = *(const float4*)&bias2[nc+4];
    bb[0]+=c0.x; bb[1]+=c0.y; bb[2]+=c0.z; bb[3]+=c0.w;
    bb[4]+=c1.x; bb[5]+=c1.y; bb[6]+=c1.z; bb[7]+=c1.w;
  }
#pragma unroll
  for (int i = 0; i < 8; ++i) {
    const int m = m0 + ty * 8 + i;
    float4 o0 = make_float4(acc[i][0]+bb[0], acc[i][1]+bb[1], acc[i][2]+bb[2], acc[i][3]+bb[3]);
    float4 o1 = make_float4(acc[i][4]+bb[4], acc[i][5]+bb[5], acc[i][6]+bb[6], acc[i][7]+bb[7]);
    if (gmode) {
      const int b = m >> 9, tt = m & 511, g = nc >> 9, j = nc & 511;
      const size_t base = ((size_t)(tt * 4 + g) * 32 + b) * 512 + j;
      *(float4*)&C[base] = o0; *(float4*)&C[base + 4] = o1;
    } else {
      *(float4*)&C[(size_t)m * N + nc] = o0;
      *(float4*)&C[(size_t)m * N + nc + 4] = o1;
    }
  }
}

// ---------------------------------------------------------------------------
// Persistent LSTM recurrence, TAGGED-PAIR protocol (single LLC RT per step).
// Geometry = round-6 PASS (128 WG x 256 thr, 4 j/WG, Whh in registers).
// hT2[2 parity][512 j][32 b] of float2 (value, tag): producer publishes h as
// ONE aligned 8-byte sc0 sc1 store; consumers poll the data's own tags.
// Coverage: 2 batches x 16 dwordx4/thread x 256 thr x 2 values = 16384 = 512x32.
// Retry re-issues only stale loads (exec-masked conditional asm).
// ---------------------------------------------------------------------------
__global__ __launch_bounds__(256, 1) void lstm_rec(
    const float* __restrict__ G,     // [512 t][4 g][32 b][512 j]
    const float* __restrict__ Whh,   // [2048][512]
    float* __restrict__ Hout,        // [(b*512+t)*512 + j]
    float2* __restrict__ hT2) {      // [2][512 j][32 b] (value, tag)
  __shared__ __align__(16) float h_lds[512 * PADH];
  __shared__ __align__(16) float red2[4][16][36];
  __shared__ __align__(16) float pre_s[2][4][32][4];

  const int tid = threadIdx.x;
  const int wg  = blockIdx.x;
  const int j0  = wg * 4;
  const int lane = tid & 63;
  const int wv   = tid >> 6;

  // compute decode (r6-proven)
  const int kq = tid >> 4;          // [0,16): k-slice
  const int jj = tid & 3;           // [0,4)
  const int bq = (tid >> 2) & 3;    // [0,4)
  const int b0 = bq * 8;

  // Whh slice into registers: w_reg[i][g] = Whh[g*512 + j0 + jj][kq + 16*i]
  float w_reg[32][4];
#pragma unroll
  for (int g = 0; g < 4; ++g) {
    const float* wrow = Whh + (size_t)(g * 512 + j0 + jj) * 512 + kq;
#pragma unroll
    for (int i = 0; i < 32; ++i) w_reg[i][g] = wrow[16 * i];
  }

  // owner decode (tid < 128)
  const int ob  = tid >> 2;             // [0,32)
  const int ojj = tid & 3;              // [0,4)
  const int rl  = (ob >> 3) * 4 + ojj;  // red2 l-index
  const int rbl = ob & 7;               // b_local
  float c_reg = 0.f;

  // G prefetch decode (waves 2,3): 128 threads cover 4 g x 32 b (float4 of j)
  const int pid = tid - 128;
  const int pg = pid >> 5, pb = pid & 31;
  float4 gpre;
  if (tid >= 128)
    gpre = *(const float4*)&G[(((size_t)0 * 4 + pg) * 32 + pb) * 512 + j0];

  for (int t = 0; t < 512; ++t) {
    const int buf = t & 1;

    // commit prefetched G(t) to LDS
    if (tid >= 128)
      *(float4*)&pre_s[buf][pg][pb][0] = gpre;

    // ---- tagged staging: poll-on-data, two 16-load batches ----
    const float* h2f = (const float*)(hT2 + (size_t)buf * 16384);
    const float ftag = (float)t;
    float4 hv[16];

#pragma unroll
    for (int half = 0; half < 2; ++half) {
      const int ibase = half * 4096;   // idx4 offset (batch B covers j >= 256)
#pragma unroll
      for (int it = 0; it < 16; ++it)
        asm volatile("global_load_dwordx4 %0, %1, off sc0 sc1"
                     : "=&v"(hv[it])
                     : "v"(h2f + (size_t)(ibase + tid + it * 256) * 4));
      asm volatile("s_waitcnt vmcnt(0)" ::: "memory");
      for (;;) {
        bool ok = true;
#pragma unroll
        for (int it = 0; it < 16; ++it)
          ok = ok && (hv[it].y == ftag) && (hv[it].w == ftag);
        if (__all(ok)) break;
#pragma unroll
        for (int it = 0; it < 16; ++it)
          if (hv[it].y != ftag || hv[it].w != ftag)
            asm volatile("global_load_dwordx4 %0, %1, off sc0 sc1"
                         : "=&v"(hv[it])
                         : "v"(h2f + (size_t)(ibase + tid + it * 256) * 4));
        asm volatile("s_waitcnt vmcnt(0)" ::: "memory");
      }
      __builtin_amdgcn_sched_barrier(0);
      // LDS write: idx4 covers pairs s0=2*idx4 (j=idx4>>4, col=2*(idx4&15))
#pragma unroll
      for (int it = 0; it < 16; ++it) {
        const int idx4 = ibase + tid + it * 256;
        *(float2*)&h_lds[(idx4 >> 4) * PADH + 2 * (idx4 & 15)] =
            make_float2(hv[it].x, hv[it].z);
      }
    }
    __syncthreads();

    // issue G prefetch for t+1 (completes during FMA/reduce)
    if (tid >= 128 && t + 1 < 512)
      gpre = *(const float4*)&G[(((size_t)(t + 1) * 4 + pg) * 32 + pb) * 512 + j0];

    // FMA: acc2[b-pair][g] over 32 k's (k = kq + 16*i), float2-packed
    float2 acc2[4][4] = {};
#pragma unroll
    for (int i = 0; i < 32; ++i) {
      const int k = kq + 16 * i;
      const float2* hp2 = (const float2*)&h_lds[k * PADH + b0];
      float2 h01 = hp2[0], h23 = hp2[1], h45 = hp2[2], h67 = hp2[3];
#pragma unroll
      for (int g = 0; g < 4; ++g) {
        const float w = w_reg[i][g];
        acc2[0][g] = f2fma(h01, w, acc2[0][g]);
        acc2[1][g] = f2fma(h23, w, acc2[1][g]);
        acc2[2][g] = f2fma(h45, w, acc2[2][g]);
        acc2[3][g] = f2fma(h67, w, acc2[3][g]);
      }
    }
    float acc[8][4];
#pragma unroll
    for (int x = 0; x < 4; ++x)
#pragma unroll
      for (int g = 0; g < 4; ++g) {
        acc[2*x][g]   = acc2[x][g].x;
        acc[2*x+1][g] = acc2[x][g].y;
      }

    // wave-local reduce over 4 kq groups (lane bits 4,5)
#pragma unroll
    for (int bi = 0; bi < 8; ++bi)
#pragma unroll
      for (int g = 0; g < 4; ++g) {
        float v = acc[bi][g];
        v += __shfl_down(v, 32, 64);
        v += __shfl_down(v, 16, 64);
        acc[bi][g] = v;
      }
    if (lane < 16) {
#pragma unroll
      for (int e = 0; e < 32; ++e) red2[wv][lane][e] = acc[e >> 2][e & 3];
    }
    __syncthreads();

    // owners (tid<128): cross-wave combine + LSTM cell + tagged publish
    if (tid < 128) {
      float4 s0 = *(const float4*)&red2[0][rl][rbl * 4];
      float4 s1 = *(const float4*)&red2[1][rl][rbl * 4];
      float4 s2 = *(const float4*)&red2[2][rl][rbl * 4];
      float4 s3 = *(const float4*)&red2[3][rl][rbl * 4];
      const float gi = (s0.x + s1.x) + (s2.x + s3.x) + pre_s[buf][0][ob][ojj];
      const float gf = (s0.y + s1.y) + (s2.y + s3.y) + pre_s[buf][1][ob][ojj];
      const float gg = (s0.z + s1.z) + (s2.z + s3.z) + pre_s[buf][2][ob][ojj];
      const float go = (s0.w + s1.w) + (s2.w + s3.w) + pre_s[buf][3][ob][ojj];
      const float iv = sigf(gi);
      const float fv = sigf(gf);
      const float gv = tanhf(gg);
      const float ov = sigf(go);
      const float c = fv * c_reg + iv * gv;
      c_reg = c;
      const float h = ov * tanhf(c);
      float2* hnxt = hT2 + (size_t)((t + 1) & 1) * 16384;
      const float2 pub = make_float2(h, (float)(t + 1));
      asm volatile("global_store_dwordx2 %0, %1, off sc0 sc1"
                   :: "v"(&hnxt[(j0 + ojj) * 32 + ob]), "v"(pub) : "memory");
      Hout[((size_t)ob * 512 + t) * 512 + j0 + ojj] = h;
    }
  }
}

// ---------------------------------------------------------------------------
// Fused attention: out[b,q] = (1/8)*sum_h softmax_{d<=q}(QK^T/8)[d]*H2[b,q,d]*Wo[d] + bo
// ---------------------------------------------------------------------------
__device__ __forceinline__ int kswz(int row, int col) {
  return row * 64 + (col ^ (((row >> 2) & 7) << 2));
}

__global__ __launch_bounds__(256) void attn_kernel(
    const float* __restrict__ Qg, const float* __restrict__ Kg,
    const float* __restrict__ H2, const float* __restrict__ Wo,
    const float* __restrict__ bo, float* __restrict__ out) {
  __shared__ float Ks[64 * 64];
  __shared__ float part[4][16][68];
  __shared__ float s[16][512];
  __shared__ float Wo_s[512];

  const int tid = threadIdx.x;
  const int qt = blockIdx.x, b = blockIdx.y;
  const int q0 = qt * 16;
  const int dd = tid >> 6, qq = (tid >> 4) & 3, kq = tid & 15;
  const int srow = tid >> 4, slane = tid & 15;

  Wo_s[tid] = Wo[tid];
  Wo_s[256 + tid] = Wo[256 + tid];

  float out_reg = 0.f;
  const int kcmax = (q0 + 15) >> 6;

  for (int h = 0; h < 8; ++h) {
    float qreg[4][16];
#pragma unroll
    for (int r = 0; r < 4; ++r) {
      const float* qrow = Qg + ((size_t)(b * 512) + q0 + qq * 4 + r) * 512 + h * 64 + dd * 16;
#pragma unroll
      for (int i = 0; i < 16; i += 4) {
        float4 v = *(const float4*)(qrow + i);
        qreg[r][i] = v.x; qreg[r][i+1] = v.y; qreg[r][i+2] = v.z; qreg[r][i+3] = v.w;
      }
    }

    for (int kc = 0; kc <= kcmax; ++kc) {
      __syncthreads();
#pragma unroll
      for (int it = 0; it < 4; ++it) {
        const int f = tid * 4 + it * 1024;
        const int kk = f >> 6, d = f & 63;
        float4 v = *(const float4*)(Kg + ((size_t)(b * 512) + kc * 64 + kk) * 512 + h * 64 + d);
        Ks[kswz(d + 0, kk)] = v.x;
        Ks[kswz(d + 1, kk)] = v.y;
        Ks[kswz(d + 2, kk)] = v.z;
        Ks[kswz(d + 3, kk)] = v.w;
      }
      __syncthreads();

      float acc[4][4] = {};
#pragma unroll
      for (int i = 0; i < 16; ++i) {
        const int row = dd * 16 + i;
        float4 k4 = *(const float4*)&Ks[kswz(row, kq * 4)];
#pragma unroll
        for (int r = 0; r < 4; ++r) {
          acc[r][0] += qreg[r][i] * k4.x;
          acc[r][1] += qreg[r][i] * k4.y;
          acc[r][2] += qreg[r][i] * k4.z;
          acc[r][3] += qreg[r][i] * k4.w;
        }
      }
#pragma unroll
      for (int r = 0; r < 4; ++r)
        *(float4*)&part[dd][qq * 4 + r][kq * 4] =
            make_float4(acc[r][0], acc[r][1], acc[r][2], acc[r][3]);
      __syncthreads();
      {
        const int qi = tid >> 4, c = tid & 15;
        float4 p0 = *(const float4*)&part[0][qi][c * 4];
        float4 p1 = *(const float4*)&part[1][qi][c * 4];
        float4 p2 = *(const float4*)&part[2][qi][c * 4];
        float4 p3 = *(const float4*)&part[3][qi][c * 4];
        float4 r;
        r.x = ((p0.x + p1.x) + (p2.x + p3.x)) * 0.125f;
        r.y = ((p0.y + p1.y) + (p2.y + p3.y)) * 0.125f;
        r.z = ((p0.z + p1.z) + (p2.z + p3.z)) * 0.125f;
        r.w = ((p0.w + p1.w) + (p2.w + p3.w)) * 0.125f;
        *(float4*)&s[qi][kc * 64 + c * 4] = r;
      }
    }
    __syncthreads();

    const int q = q0 + srow;
    const int count = q + 1;
    const float* sp = &s[srow][0];
    float m = -1e30f;
    for (int d = slane; d < count; d += 16) m = fmaxf(m, sp[d]);
    m = fmaxf(m, __shfl_xor(m, 1, 64));
    m = fmaxf(m, __shfl_xor(m, 2, 64));
    m = fmaxf(m, __shfl_xor(m, 4, 64));
    m = fmaxf(m, __shfl_xor(m, 8, 64));
    float z = 0.f, zw = 0.f;
    const float* h2row = H2 + ((size_t)(b * 512) + q) * 512;
    for (int d = slane; d < count; d += 16) {
      const float e = __expf(sp[d] - m);
      z += e;
      zw += e * h2row[d] * Wo_s[d];
    }
    z += __shfl_xor(z, 1, 64); z += __shfl_xor(z, 2, 64);
    z += __shfl_xor(z, 4, 64); z += __shfl_xor(z, 8, 64);
    zw += __shfl_xor(zw, 1, 64); zw += __shfl_xor(zw, 2, 64);
    zw += __shfl_xor(zw, 4, 64); zw += __shfl_xor(zw, 8, 64);
    out_reg += zw / z;
    __syncthreads();
  }

  if (slane == 0)
    out[b * 512 + q0 + srow] = out_reg * 0.125f + bo[0];
}

// ---------------------------------------------------------------------------
extern "C" void kernel_launch(void* const* d_in, const int* in_sizes, int n_in,
                              void* d_out, int out_size, void* d_ws, size_t ws_size,
                              hipStream_t stream) {
  const float* x    = (const float*)d_in[0];
  const float* Wih0 = (const float*)d_in[1];
  const float* Whh0 = (const float*)d_in[2];
  const float* bih0 = (const float*)d_in[3];
  const float* bhh0 = (const float*)d_in[4];
  const float* Wih1 = (const float*)d_in[5];
  const float* Whh1 = (const float*)d_in[6];
  const float* bih1 = (const float*)d_in[7];
  const float* bhh1 = (const float*)d_in[8];
  const float* Wq   = (const float*)d_in[9];
  const float* bq   = (const float*)d_in[10];
  const float* Wk   = (const float*)d_in[11];
  const float* bk   = (const float*)d_in[12];
  const float* Wo   = (const float*)d_in[13];
  const float* bo   = (const float*)d_in[14];
  float* out = (float*)d_out;

  float* ws = (float*)d_ws;
  const size_t M = 16384;
  float* G  = ws;                                    // 16384*2048 floats
  float* H1 = G  + (size_t)16384 * 2048;             // 16384*512
  float* H2 = H1 + (size_t)16384 * 512;              // 16384*512
  float2* hT2 = (float2*)(H2 + (size_t)16384 * 512); // 2*16384 float2 (value, tag)
  float* Qb = H1;   // reuse (H1 dead after layer-1 G gemm)
  float* Kb = G;    // reuse (G dead after layer-1 recurrence)

  // zero tagged h state (tag 0 == step-0 expectation, h0 = 0)
  hipMemsetAsync(hT2, 0, 2 * 16384 * sizeof(float2), stream);

  // layer 0
  gemm128<<<dim3(2048 / 128, M / 128), 256, 0, stream>>>(x, Wih0, bih0, bhh0, G,
                                                         (int)M, 2048, 256, 1);
  lstm_rec<<<NWG, 256, 0, stream>>>(G, Whh0, H1, hT2);

  // layer 1 (re-zero tags+values; tags restart at 0 per layer)
  hipMemsetAsync(hT2, 0, 2 * 16384 * sizeof(float2), stream);
  gemm128<<<dim3(2048 / 128, M / 128), 256, 0, stream>>>(H1, Wih1, bih1, bhh1, G,
                                                         (int)M, 2048, 512, 1);
  lstm_rec<<<NWG, 256, 0, stream>>>(G, Whh1, H2, hT2);

  // Q/K projections
  gemm128<<<dim3(512 / 128, M / 128), 256, 0, stream>>>(H2, Wq, bq, nullptr, Qb,
                                                        (int)M, 512, 512, 0);
  gemm128<<<dim3(512 / 128, M / 128), 256, 0, stream>>>(H2, Wk, bk, nullptr, Kb,
                                                        (int)M, 512, 512, 0);

  // fused causal attention + head-mean + gated output
  attn_kernel<<<dim3(32, 32), 256, 0, stream>>>(Qb, Kb, H2, Wo, bo, out);
}

// Round 9
// 4845.843 us; speedup vs baseline: 2.6079x; 1.8706x over previous
//
#include <hip/hip_runtime.h>
#include <cmath>

#define NBAT 32
#define PADH2 6    // h_lds row stride: 4 batch floats + 2 pad (see bank note)
#define NWG  256   // 8 batch-domains x 32 j-groups; 16 j x 4 b per WG

__device__ __forceinline__ float sigf(float x) { return 1.f / (1.f + __expf(-x)); }

__device__ __forceinline__ float2 f2fma(float2 a, float s, float2 c) {
  return make_float2(fmaf(a.x, s, c.x), fmaf(a.y, s, c.y));
}

// XOR swizzle on 16B chunks: spreads stride-8 float reads across bank quads.
__device__ __forceinline__ int gswz(int c) { return c ^ (c >> 3); }

// ---------------------------------------------------------------------------
// GEMM: C[M,N] = A[M,K] @ B[N,K]^T + bias1 (+ bias2), 128x128 tile, 8x8/thread
// gmode=1: scatter-store into G layout [t][g][b][j] (row m = b*512+t, col n = g*512+j)
// ---------------------------------------------------------------------------
__global__ __launch_bounds__(256, 2) void gemm128(
    const float* __restrict__ A, const float* __restrict__ B,
    const float* __restrict__ bias1, const float* __restrict__ bias2,
    float* __restrict__ C, int M, int N, int K, int gmode) {
  __shared__ __align__(16) float As[8][132];
  __shared__ __align__(16) float Bs[8][132];
  const int tid = threadIdx.x;
  const int n0 = blockIdx.x * 128, m0 = blockIdx.y * 128;
  const int lm = tid & 127, kh = tid >> 7;   // staging: row, k-half
  const int tx = tid & 15, ty = tid >> 4;    // compute: col group, row group
  const int colp = (gswz(lm >> 2) << 2) | (lm & 3);
  const int ca0 = gswz(2 * ty) * 4, ca1 = gswz(2 * ty + 1) * 4;
  const int cb0 = gswz(2 * tx) * 4, cb1 = gswz(2 * tx + 1) * 4;
  const float* Ap = A + (size_t)(m0 + lm) * K + kh * 4;
  const float* Bp = B + (size_t)(n0 + lm) * K + kh * 4;
  float acc[8][8] = {};
  float4 av = *(const float4*)Ap;
  float4 bv = *(const float4*)Bp;
  const int nk = K / 8;
  for (int kt = 0; kt < nk; ++kt) {
    __syncthreads();
    As[kh*4+0][colp] = av.x; As[kh*4+1][colp] = av.y;
    As[kh*4+2][colp] = av.z; As[kh*4+3][colp] = av.w;
    Bs[kh*4+0][colp] = bv.x; Bs[kh*4+1][colp] = bv.y;
    Bs[kh*4+2][colp] = bv.z; Bs[kh*4+3][colp] = bv.w;
    __syncthreads();
    if (kt + 1 < nk) {
      av = *(const float4*)(Ap + (kt + 1) * 8);
      bv = *(const float4*)(Bp + (kt + 1) * 8);
    }
#pragma unroll
    for (int kk = 0; kk < 8; ++kk) {
      float4 a0 = *(const float4*)&As[kk][ca0];
      float4 a1 = *(const float4*)&As[kk][ca1];
      float4 b0 = *(const float4*)&Bs[kk][cb0];
      float4 b1 = *(const float4*)&Bs[kk][cb1];
      float ar[8] = {a0.x,a0.y,a0.z,a0.w,a1.x,a1.y,a1.z,a1.w};
      float br[8] = {b0.x,b0.y,b0.z,b0.w,b1.x,b1.y,b1.z,b1.w};
#pragma unroll
      for (int i = 0; i < 8; ++i)
#pragma unroll
        for (int j = 0; j < 8; ++j)
          acc[i][j] += ar[i] * br[j];
    }
  }
  const int nc = n0 + tx * 8;
  float bb[8];
  { float4 c0 = *(const float4*)&bias1[nc], c1 = *(const float4*)&bias1[nc+4];
    bb[0]=c0.x; bb[1]=c0.y; bb[2]=c0.z; bb[3]=c0.w;
    bb[4]=c1.x; bb[5]=c1.y; bb[6]=c1.z; bb[7]=c1.w; }
  if (bias2) {
    float4 c0 = *(const float4*)&bias2[nc], c1 = *(const float4*)&bias2[nc+4];
    bb[0]+=c0.x; bb[1]+=c0.y; bb[2]+=c0.z; bb[3]+=c0.w;
    bb[4]+=c1.x; bb[5]+=c1.y; bb[6]+=c1.z; bb[7]+=c1.w;
  }
#pragma unroll
  for (int i = 0; i < 8; ++i) {
    const int m = m0 + ty * 8 + i;
    float4 o0 = make_float4(acc[i][0]+bb[0], acc[i][1]+bb[1], acc[i][2]+bb[2], acc[i][3]+bb[3]);
    float4 o1 = make_float4(acc[i][4]+bb[4], acc[i][5]+bb[5], acc[i][6]+bb[6], acc[i][7]+bb[7]);
    if (gmode) {
      const int b = m >> 9, tt = m & 511, g = nc >> 9, j = nc & 511;
      const size_t base = ((size_t)(tt * 4 + g) * 32 + b) * 512 + j;
      *(float4*)&C[base] = o0; *(float4*)&C[base + 4] = o1;
    } else {
      *(float4*)&C[(size_t)m * N + nc] = o0;
      *(float4*)&C[(size_t)m * N + nc + 4] = o1;
    }
  }
}

// ---------------------------------------------------------------------------
// Persistent LSTM recurrence, BATCH-SPLIT domains + tagged-pair protocol.
// 256 WGs x 256 thr = 8 independent domains (4 batches each) x 32 j-groups.
// WG (bg, jg) owns j in [16*jg, 16*jg+16), b in [4*bg, 4*bg+4).
// hT2[2 parity][8 bg][512 j][4 bl] float2 (value, tag): producer publishes h
// as ONE aligned 8B sc0 sc1 store; consumers poll tags of their domain only.
// Coverage: 4 dwordx4/thr x 256 thr = 1024 -> 2048 pairs = 512 j x 4 bl. FULL.
// ---------------------------------------------------------------------------
__global__ __launch_bounds__(256, 1) void lstm_rec(
    const float* __restrict__ G,     // [512 t][4 g][32 b][512 j]
    const float* __restrict__ Whh,   // [2048][512]
    float* __restrict__ Hout,        // [(b*512+t)*512 + j]
    float2* __restrict__ hT2) {      // [2][8][512][4] (value, tag)
  __shared__ __align__(16) float h_lds[512 * PADH2];
  __shared__ __align__(16) float red2[4][16][20];
  __shared__ __align__(16) float pre_s[2][4][4][16];  // [buf][g][bl][j]

  const int tid = threadIdx.x;
  const int wg  = blockIdx.x;
  const int bg  = wg >> 5;          // batch group [0,8)
  const int jg  = wg & 31;          // j group [0,32)
  const int j0  = jg * 16;
  const int lane = tid & 63;
  const int wv   = tid >> 6;

  // FMA decode: per-wave kq's are CONSECUTIVE (4w+lane>>4) -> h_lds rows k,
  // k+1,k+2,k+3 at stride 6 floats -> banks distinct (conflict-free b64).
  const int kq = tid >> 4;          // [0,16): k-slice (32 k each)
  const int jj = tid & 15;          // [0,16): j within group

  // Whh slice: w_reg[i][g] = Whh[g*512 + j0 + jj][kq + 16*i]
  float w_reg[32][4];
#pragma unroll
  for (int g = 0; g < 4; ++g) {
    const float* wrow = Whh + (size_t)(g * 512 + j0 + jj) * 512 + kq;
#pragma unroll
    for (int i = 0; i < 32; ++i) w_reg[i][g] = wrow[16 * i];
  }

  // owner decode (tid < 64): output (bl=ob, j=j0+ojj)
  const int ob  = tid >> 4;             // [0,4)
  const int ojj = tid & 15;             // [0,16)
  float c_reg = 0.f;

  // G prefetch decode (tid in [128,256)): 128 thr x float2 = 256 = 4g x 4b x 16j
  const int pid = tid - 128;
  const int pg = pid >> 5, pb = (pid >> 3) & 3, pjh = pid & 7;
  float2 gpre;
  if (tid >= 128)
    gpre = *(const float2*)&G[(((size_t)0 * 4 + pg) * 32 + bg * 4 + pb) * 512 + j0 + pjh * 2];

  const size_t dom = (size_t)bg * 2048;   // domain offset in pairs

  for (int t = 0; t < 512; ++t) {
    const int buf = t & 1;

    // commit prefetched G(t) to LDS
    if (tid >= 128)
      *(float2*)&pre_s[buf][pg][pb][pjh * 2] = gpre;

    // ---- tagged staging: 4 dwordx4/thread, poll-on-data ----
    const float* h2f = (const float*)(hT2 + (size_t)buf * 16384 + dom);
    const float ftag = (float)t;
    float4 hv[4];
#pragma unroll
    for (int it = 0; it < 4; ++it)
      asm volatile("global_load_dwordx4 %0, %1, off sc0 sc1"
                   : "=&v"(hv[it])
                   : "v"(h2f + (size_t)(tid + it * 256) * 4));
    asm volatile("s_waitcnt vmcnt(0)" ::: "memory");
    for (;;) {
      bool ok = true;
#pragma unroll
      for (int it = 0; it < 4; ++it)
        ok = ok && (hv[it].y == ftag) && (hv[it].w == ftag);
      if (__all(ok)) break;
#pragma unroll
      for (int it = 0; it < 4; ++it)
        if (hv[it].y != ftag || hv[it].w != ftag)
          asm volatile("global_load_dwordx4 %0, %1, off sc0 sc1"
                       : "=&v"(hv[it])
                       : "v"(h2f + (size_t)(tid + it * 256) * 4));
      asm volatile("s_waitcnt vmcnt(0)" ::: "memory");
    }
    __builtin_amdgcn_sched_barrier(0);
    // pairs p=2*idx4, p+1 -> j = idx4>>1, bl = (idx4&1)*2, +1
#pragma unroll
    for (int it = 0; it < 4; ++it) {
      const int idx4 = tid + it * 256;
      *(float2*)&h_lds[(idx4 >> 1) * PADH2 + (idx4 & 1) * 2] =
          make_float2(hv[it].x, hv[it].z);
    }
    __syncthreads();

    // issue G prefetch for t+1 (completes during FMA/reduce)
    if (tid >= 128 && t + 1 < 512)
      gpre = *(const float2*)&G[(((size_t)(t + 1) * 4 + pg) * 32 + bg * 4 + pb) * 512 + j0 + pjh * 2];

    // FMA: acc2[b-pair][g] over 32 k's (k = kq + 16*i)
    float2 acc2[2][4] = {};
#pragma unroll
    for (int i = 0; i < 32; ++i) {
      const int k = kq + 16 * i;
      const float2* hp2 = (const float2*)&h_lds[k * PADH2];
      float2 h01 = hp2[0], h23 = hp2[1];
#pragma unroll
      for (int g = 0; g < 4; ++g) {
        const float w = w_reg[i][g];
        acc2[0][g] = f2fma(h01, w, acc2[0][g]);
        acc2[1][g] = f2fma(h23, w, acc2[1][g]);
      }
    }
    float acc[4][4];
#pragma unroll
    for (int x = 0; x < 2; ++x)
#pragma unroll
      for (int g = 0; g < 4; ++g) {
        acc[2*x][g]   = acc2[x][g].x;
        acc[2*x+1][g] = acc2[x][g].y;
      }

    // in-wave reduce over 4 consecutive kq's (lane bits 4,5)
#pragma unroll
    for (int bl = 0; bl < 4; ++bl)
#pragma unroll
      for (int g = 0; g < 4; ++g) {
        float v = acc[bl][g];
        v += __shfl_down(v, 32, 64);
        v += __shfl_down(v, 16, 64);
        acc[bl][g] = v;
      }
    if (lane < 16) {
#pragma unroll
      for (int e = 0; e < 16; ++e) red2[wv][lane][e] = acc[e >> 2][e & 3];
    }
    __syncthreads();

    // owners (tid<64): cross-wave combine + LSTM cell + tagged publish
    if (tid < 64) {
      float4 s0 = *(const float4*)&red2[0][ojj][ob * 4];
      float4 s1 = *(const float4*)&red2[1][ojj][ob * 4];
      float4 s2 = *(const float4*)&red2[2][ojj][ob * 4];
      float4 s3 = *(const float4*)&red2[3][ojj][ob * 4];
      const float gi = (s0.x + s1.x) + (s2.x + s3.x) + pre_s[buf][0][ob][ojj];
      const float gf = (s0.y + s1.y) + (s2.y + s3.y) + pre_s[buf][1][ob][ojj];
      const float gg = (s0.z + s1.z) + (s2.z + s3.z) + pre_s[buf][2][ob][ojj];
      const float go = (s0.w + s1.w) + (s2.w + s3.w) + pre_s[buf][3][ob][ojj];
      const float iv = sigf(gi);
      const float fv = sigf(gf);
      const float gv = tanhf(gg);
      const float ov = sigf(go);
      const float c = fv * c_reg + iv * gv;
      c_reg = c;
      const float h = ov * tanhf(c);
      float2* hnxt = hT2 + (size_t)((t + 1) & 1) * 16384 + dom;
      const float2 pub = make_float2(h, (float)(t + 1));
      asm volatile("global_store_dwordx2 %0, %1, off sc0 sc1"
                   :: "v"(&hnxt[(j0 + ojj) * 4 + ob]), "v"(pub) : "memory");
      Hout[((size_t)(bg * 4 + ob) * 512 + t) * 512 + j0 + ojj] = h;
    }
    // no trailing barrier needed: waves 1-3 block on next-step tag poll, which
    // requires this WG's own wave-0 publish; red2/h_lds writes at t+1 therefore
    // postdate all step-t reads.
  }
}

// ---------------------------------------------------------------------------
// Fused attention: out[b,q] = (1/8)*sum_h softmax_{d<=q}(QK^T/8)[d]*H2[b,q,d]*Wo[d] + bo
// ---------------------------------------------------------------------------
__device__ __forceinline__ int kswz(int row, int col) {
  return row * 64 + (col ^ (((row >> 2) & 7) << 2));
}

__global__ __launch_bounds__(256) void attn_kernel(
    const float* __restrict__ Qg, const float* __restrict__ Kg,
    const float* __restrict__ H2, const float* __restrict__ Wo,
    const float* __restrict__ bo, float* __restrict__ out) {
  __shared__ float Ks[64 * 64];
  __shared__ float part[4][16][68];
  __shared__ float s[16][512];
  __shared__ float Wo_s[512];

  const int tid = threadIdx.x;
  const int qt = blockIdx.x, b = blockIdx.y;
  const int q0 = qt * 16;
  const int dd = tid >> 6, qq = (tid >> 4) & 3, kq = tid & 15;
  const int srow = tid >> 4, slane = tid & 15;

  Wo_s[tid] = Wo[tid];
  Wo_s[256 + tid] = Wo[256 + tid];

  float out_reg = 0.f;
  const int kcmax = (q0 + 15) >> 6;

  for (int h = 0; h < 8; ++h) {
    float qreg[4][16];
#pragma unroll
    for (int r = 0; r < 4; ++r) {
      const float* qrow = Qg + ((size_t)(b * 512) + q0 + qq * 4 + r) * 512 + h * 64 + dd * 16;
#pragma unroll
      for (int i = 0; i < 16; i += 4) {
        float4 v = *(const float4*)(qrow + i);
        qreg[r][i] = v.x; qreg[r][i+1] = v.y; qreg[r][i+2] = v.z; qreg[r][i+3] = v.w;
      }
    }

    for (int kc = 0; kc <= kcmax; ++kc) {
      __syncthreads();
#pragma unroll
      for (int it = 0; it < 4; ++it) {
        const int f = tid * 4 + it * 1024;
        const int kk = f >> 6, d = f & 63;
        float4 v = *(const float4*)(Kg + ((size_t)(b * 512) + kc * 64 + kk) * 512 + h * 64 + d);
        Ks[kswz(d + 0, kk)] = v.x;
        Ks[kswz(d + 1, kk)] = v.y;
        Ks[kswz(d + 2, kk)] = v.z;
        Ks[kswz(d + 3, kk)] = v.w;
      }
      __syncthreads();

      float acc[4][4] = {};
#pragma unroll
      for (int i = 0; i < 16; ++i) {
        const int row = dd * 16 + i;
        float4 k4 = *(const float4*)&Ks[kswz(row, kq * 4)];
#pragma unroll
        for (int r = 0; r < 4; ++r) {
          acc[r][0] += qreg[r][i] * k4.x;
          acc[r][1] += qreg[r][i] * k4.y;
          acc[r][2] += qreg[r][i] * k4.z;
          acc[r][3] += qreg[r][i] * k4.w;
        }
      }
#pragma unroll
      for (int r = 0; r < 4; ++r)
        *(float4*)&part[dd][qq * 4 + r][kq * 4] =
            make_float4(acc[r][0], acc[r][1], acc[r][2], acc[r][3]);
      __syncthreads();
      {
        const int qi = tid >> 4, c = tid & 15;
        float4 p0 = *(const float4*)&part[0][qi][c * 4];
        float4 p1 = *(const float4*)&part[1][qi][c * 4];
        float4 p2 = *(const float4*)&part[2][qi][c * 4];
        float4 p3 = *(const float4*)&part[3][qi][c * 4];
        float4 r;
        r.x = ((p0.x + p1.x) + (p2.x + p3.x)) * 0.125f;
        r.y = ((p0.y + p1.y) + (p2.y + p3.y)) * 0.125f;
        r.z = ((p0.z + p1.z) + (p2.z + p3.z)) * 0.125f;
        r.w = ((p0.w + p1.w) + (p2.w + p3.w)) * 0.125f;
        *(float4*)&s[qi][kc * 64 + c * 4] = r;
      }
    }
    __syncthreads();

    const int q = q0 + srow;
    const int count = q + 1;
    const float* sp = &s[srow][0];
    float m = -1e30f;
    for (int d = slane; d < count; d += 16) m = fmaxf(m, sp[d]);
    m = fmaxf(m, __shfl_xor(m, 1, 64));
    m = fmaxf(m, __shfl_xor(m, 2, 64));
    m = fmaxf(m, __shfl_xor(m, 4, 64));
    m = fmaxf(m, __shfl_xor(m, 8, 64));
    float z = 0.f, zw = 0.f;
    const float* h2row = H2 + ((size_t)(b * 512) + q) * 512;
    for (int d = slane; d < count; d += 16) {
      const float e = __expf(sp[d] - m);
      z += e;
      zw += e * h2row[d] * Wo_s[d];
    }
    z += __shfl_xor(z, 1, 64); z += __shfl_xor(z, 2, 64);
    z += __shfl_xor(z, 4, 64); z += __shfl_xor(z, 8, 64);
    zw += __shfl_xor(zw, 1, 64); zw += __shfl_xor(zw, 2, 64);
    zw += __shfl_xor(zw, 4, 64); zw += __shfl_xor(zw, 8, 64);
    out_reg += zw / z;
    __syncthreads();
  }

  if (slane == 0)
    out[b * 512 + q0 + srow] = out_reg * 0.125f + bo[0];
}

// ---------------------------------------------------------------------------
extern "C" void kernel_launch(void* const* d_in, const int* in_sizes, int n_in,
                              void* d_out, int out_size, void* d_ws, size_t ws_size,
                              hipStream_t stream) {
  const float* x    = (const float*)d_in[0];
  const float* Wih0 = (const float*)d_in[1];
  const float* Whh0 = (const float*)d_in[2];
  const float* bih0 = (const float*)d_in[3];
  const float* bhh0 = (const float*)d_in[4];
  const float* Wih1 = (const float*)d_in[5];
  const float* Whh1 = (const float*)d_in[6];
  const float* bih1 = (const float*)d_in[7];
  const float* bhh1 = (const float*)d_in[8];
  const float* Wq   = (const float*)d_in[9];
  const float* bq   = (const float*)d_in[10];
  const float* Wk   = (const float*)d_in[11];
  const float* bk   = (const float*)d_in[12];
  const float* Wo   = (const float*)d_in[13];
  const float* bo   = (const float*)d_in[14];
  float* out = (float*)d_out;

  float* ws = (float*)d_ws;
  const size_t M = 16384;
  float* G  = ws;                                    // 16384*2048 floats
  float* H1 = G  + (size_t)16384 * 2048;             // 16384*512
  float* H2 = H1 + (size_t)16384 * 512;              // 16384*512
  float2* hT2 = (float2*)(H2 + (size_t)16384 * 512); // 2*8*512*4 = 32768 pairs
  float* Qb = H1;   // reuse (H1 dead after layer-1 G gemm)
  float* Kb = G;    // reuse (G dead after layer-1 recurrence)

  // zero tagged h state (tag 0 == step-0 expectation, h0 = 0)
  hipMemsetAsync(hT2, 0, 2 * 16384 * sizeof(float2), stream);

  // layer 0
  gemm128<<<dim3(2048 / 128, M / 128), 256, 0, stream>>>(x, Wih0, bih0, bhh0, G,
                                                         (int)M, 2048, 256, 1);
  lstm_rec<<<NWG, 256, 0, stream>>>(G, Whh0, H1, hT2);

  // layer 1 (re-zero tags+values; tags restart at 0 per layer)
  hipMemsetAsync(hT2, 0, 2 * 16384 * sizeof(float2), stream);
  gemm128<<<dim3(2048 / 128, M / 128), 256, 0, stream>>>(H1, Wih1, bih1, bhh1, G,
                                                         (int)M, 2048, 512, 1);
  lstm_rec<<<NWG, 256, 0, stream>>>(G, Whh1, H2, hT2);

  // Q/K projections
  gemm128<<<dim3(512 / 128, M / 128), 256, 0, stream>>>(H2, Wq, bq, nullptr, Qb,
                                                        (int)M, 512, 512, 0);
  gemm128<<<dim3(512 / 128, M / 128), 256, 0, stream>>>(H2, Wk, bk, nullptr, Kb,
                                                        (int)M, 512, 512, 0);

  // fused causal attention + head-mean + gated output
  attn_kernel<<<dim3(32, 32), 256, 0, stream>>>(Qb, Kb, H2, Wo, bo, out);
}